// Round 6
// baseline (203.747 us; speedup 1.0000x reference)
//
#include <hip/hip_runtime.h>

// GAGKNNQueryAndGroup: B=4, N=8192, NPOINT=2048, C=64, NSAMPLE=32, LAMBDA=0.5
// LAMBDA == 0.5 makes the component mask numerically irrelevant:
// where(mask, d*0.5, d*0.5) == d*0.5 (exact, order-preserving). Components unused.
// The *0.5 itself is dropped: exact power-of-two scale, ordering (incl. ties)
// identical -> argsort indices identical.

#define BQ 4
#define NN_ 8192
#define NPOINT 2048
#define CF 64
#define NS 32
#define CAP 512   // candidate capacity (E[m]~120 with min-of-4-wave thetas)
#define FSTR 66   // LDS feature row stride: bank = (2s+c)%32 -> 2-way alias (free)

// ---------------- features (B,C,N) -> featsT (B,N,C) ----------------
__global__ __launch_bounds__(256) void transpose_kernel(const float* __restrict__ f,
                                                        float* __restrict__ ft) {
  __shared__ float t[32][33];
  const int b = blockIdx.z;
  const int n0 = blockIdx.x * 32;
  const int c0 = blockIdx.y * 32;
  const int tx = threadIdx.x;   // 0..31
  const int ty = threadIdx.y;   // 0..7
#pragma unroll
  for (int i = 0; i < 4; i++) {
    int c = c0 + ty + i * 8;
    t[ty + i * 8][tx] = f[(size_t)b * CF * NN_ + (size_t)c * NN_ + n0 + tx];
  }
  __syncthreads();
#pragma unroll
  for (int i = 0; i < 4; i++) {
    int nrow = n0 + ty + i * 8;
    ft[(size_t)b * NN_ * CF + (size_t)nrow * CF + c0 + tx] = t[tx][ty + i * 8];
  }
}

// ------- Fused: exact top-32 + gather + grouped write -------
// launch_bounds(256,8): evidence (R1 69% occ no-arg vs R3/R5 ~38% with ",3")
// says the 2nd arg caps resident waves/EU on this toolchain. 8 -> VGPR budget
// 64 (>= the 56 this kernel needs), up to 8 waves/EU.
__global__ __launch_bounds__(256, 8) void knn_group_kernel(
    const float* __restrict__ xyz, const float* __restrict__ new_xyz,
    const float* __restrict__ featsT, float* __restrict__ out) {
  const int q = blockIdx.x;            // b*NPOINT + p
  const int b = q >> 11;               // q / NPOINT
  const int p = q & (NPOINT - 1);
  const int tid = threadIdx.x;
  const int wave = tid >> 6;
  const int lane = tid & 63;

  __shared__ float thetas[4];
  __shared__ int cnt;
  __shared__ __align__(16) unsigned long long cand[CAP];
  __shared__ int sIdx[NS];
  __shared__ __align__(8) float ldsF[NS * FSTR];
  __shared__ float ldsX[3 * NS];

  if (tid < NS) sIdx[tid] = 0;   // defensive: no poisoned-LDS address if a slot is missed

  const float qx = new_xyz[q * 3 + 0];
  const float qy = new_xyz[q * 3 + 1];
  const float qz = new_xyz[q * 3 + 2];

  const float4* __restrict__ X4 = (const float4*)(xyz + (size_t)b * NN_ * 3);

  // ---- distance pass: thread t covers points {4t+i + 1024*jc} ----
  float d[32];
  float lmin = 3.4e38f;
#pragma unroll
  for (int jc = 0; jc < 8; jc++) {
    float4 a0 = X4[3 * tid + 768 * jc + 0];
    float4 a1 = X4[3 * tid + 768 * jc + 1];
    float4 a2 = X4[3 * tid + 768 * jc + 2];
    float px[4] = {a0.x, a0.w, a1.z, a2.y};
    float py[4] = {a0.y, a1.x, a1.w, a2.z};
    float pz[4] = {a0.z, a1.y, a2.x, a2.w};
#pragma unroll
    for (int i = 0; i < 4; i++) {
      // exact numpy f32 semantics: no FMA contraction, left-to-right sum
      float dx = px[i] - qx;
      float dy = py[i] - qy;
      float dz = pz[i] - qz;
      float dist = __fadd_rn(__fadd_rn(__fmul_rn(dx, dx), __fmul_rn(dy, dy)),
                             __fmul_rn(dz, dz));
      d[jc * 4 + i] = dist;
      lmin = fminf(lmin, dist);
    }
  }

  // ---- per-wave theta_w: register bitonic sort of the 64 lane minima ----
  // theta_w = 32nd smallest lane-min >= true global 32nd-smallest distance
  // (the 32 smallest lane minima are 32 distinct points' distances <= theta_w).
  {
    float v = lmin;
#pragma unroll
    for (int k = 2; k <= 64; k <<= 1) {
#pragma unroll
      for (int j = k >> 1; j > 0; j >>= 1) {
        float o = __shfl_xor(v, j);
        bool dirUp = ((lane & k) == 0);
        bool lower = ((lane & j) == 0);
        float mn = fminf(v, o), mx = fmaxf(v, o);
        v = (dirUp == lower) ? mn : mx;
      }
    }
    float thw = __shfl(v, 31);          // unconditional cross-lane
    if (lane == 0) thetas[wave] = thw;
  }
  if (tid == 0) cnt = 0;
  __syncthreads();
  // every theta_w is a valid global upper bound -> their min is too (tighter)
  const float theta = fminf(fminf(thetas[0], thetas[1]), fminf(thetas[2], thetas[3]));

  // ---- collect d <= theta from registers ----
#pragma unroll
  for (int j = 0; j < 32; j++) {
    if (d[j] <= theta) {
      int n = (tid << 2) + ((j >> 2) << 10) + (j & 3);
      int pos = atomicAdd(&cnt, 1);
      if (pos < CAP)
        cand[pos] = ((unsigned long long)__float_as_uint(d[j]) << 32) | (unsigned)n;
    }
  }
  __syncthreads();
  const int m = cnt < CAP ? cnt : CAP;

  // ---- exact rank by (dist_bits, idx) == stable argsort ----
  for (int i = tid; i < m; i += 256) {
    unsigned long long x = cand[i];
    int r = 0;
    for (int j = 0; j < m; j++) r += (cand[j] < x) ? 1 : 0;
    if (r < NS) sIdx[r] = (int)(unsigned)(x & 0xffffffffu);
  }
  __syncthreads();

  // ---- group epilogue: gather features + xyz, write (67,32) slab ----
  {
    // 256 threads = 32 samples x 8 readers; each reader: 32B of the 256B
    // contiguous feature row (global dwordx4), stored to LDS as float2 pairs
    // (FSTR=66 is 8B- but not 16B-aligned per row).
    int s = tid >> 3, rr = tid & 7;
    int nn = sIdx[s] & (NN_ - 1);   // clamp: logic bug -> absmax, not page fault
    const float4* src = (const float4*)(featsT + ((size_t)b * NN_ + nn) * CF);
    float4 v0 = src[rr * 2];
    float4 v1 = src[rr * 2 + 1];
    float2* dst = (float2*)(ldsF + s * FSTR + rr * 8);
    dst[0] = make_float2(v0.x, v0.y);
    dst[1] = make_float2(v0.z, v0.w);
    dst[2] = make_float2(v1.x, v1.y);
    dst[3] = make_float2(v1.z, v1.w);
  }
  if (tid < 96) {
    int dd = tid >> 5, s = tid & 31;
    int nn = sIdx[s] & (NN_ - 1);
    float qc = (dd == 0) ? qx : (dd == 1) ? qy : qz;
    ldsX[dd * NS + s] = xyz[((size_t)b * NN_ + nn) * 3 + dd] - qc;
  }
  __syncthreads();

  const int s = tid & 31;
  const int r0 = tid >> 5;
#pragma unroll
  for (int k = 0; k < 9; k++) {
    int row = r0 + k * 8;
    if (row < 67) {
      float v = (row < 3) ? ldsX[row * NS + s] : ldsF[s * FSTR + (row - 3)];
      out[(((size_t)b * 67 + row) * NPOINT + p) * NS + s] = v;
    }
  }
}

extern "C" void kernel_launch(void* const* d_in, const int* in_sizes, int n_in,
                              void* d_out, int out_size, void* d_ws, size_t ws_size,
                              hipStream_t stream) {
  const float* xyz      = (const float*)d_in[0];   // (4,8192,3)
  const float* new_xyz  = (const float*)d_in[1];   // (4,2048,3)
  // d_in[2], d_in[3]: components — unused (LAMBDA=0.5 makes mask a no-op)
  const float* features = (const float*)d_in[4];   // (4,64,8192)
  float* out = (float*)d_out;

  float* featsT = (float*)d_ws;   // 4*8192*64 f32 = 8MB

  transpose_kernel<<<dim3(NN_ / 32, CF / 32, BQ), dim3(32, 8), 0, stream>>>(features, featsT);
  knn_group_kernel<<<BQ * NPOINT, 256, 0, stream>>>(xyz, new_xyz, featsT, out);
}